// Round 2
// baseline (456.350 us; speedup 1.0000x reference)
//
#include <hip/hip_runtime.h>
#include <hip/hip_bf16.h>

#define BB 8
#define LL 200
#define HH 128
#define NHEAD 4
#define HDIM 32
#define NBLK 2
#define BL (BB * LL)

static constexpr float SQRT_H    = 11.313708498984761f;   // sqrt(128)
static constexpr float INV_SCALE = 0.17677669529663687f;  // 1/sqrt(32)
static constexpr float PADV      = -4294967295.0f;        // -2^32+1

// -------- embed: seqs[b,l,h] = item_emb[log[b,l]][h]*sqrt(H) * keep --------
__global__ void k_embed(const int* __restrict__ log_seqs,
                        const float* __restrict__ item_emb,
                        float* __restrict__ seqs) {
    int row = blockIdx.x;          // b*L + l
    int h = threadIdx.x;           // 0..127
    int idx = log_seqs[row];
    float v = (idx == 0) ? 0.f : item_emb[idx * HH + h] * SQRT_H;
    seqs[row * HH + h] = v;
}

// -------- row LayerNorm, optional residual add: y = LN(x (+ x2)) * g + b ---
__global__ void k_ln(const float* __restrict__ x, const float* __restrict__ x2,
                     const float* __restrict__ g, const float* __restrict__ bia,
                     float* __restrict__ y) {
    int row = blockIdx.x;
    int h = threadIdx.x;           // 128 threads = 2 waves
    float v = x[row * HH + h];
    if (x2) v += x2[row * HH + h];
    float s = v, s2 = v * v;
    for (int off = 32; off; off >>= 1) {
        s  += __shfl_xor(s, off);
        s2 += __shfl_xor(s2, off);
    }
    __shared__ float r1[2], r2[2];
    if ((h & 63) == 0) { r1[h >> 6] = s; r2[h >> 6] = s2; }
    __syncthreads();
    float sum = r1[0] + r1[1], sumsq = r2[0] + r2[1];
    float mean = sum * (1.f / HH);
    float var = sumsq * (1.f / HH) - mean * mean;
    float inv = 1.f / sqrtf(var + 1e-8f);
    y[row * HH + h] = (v - mean) * inv * g[h] + bia[h];
}

// -------- fused QKV row-GEMM: one block per row --------
__global__ void k_qkv(const float* __restrict__ Qin, const float* __restrict__ seqs,
                      const float* __restrict__ Wq, const float* __restrict__ bq,
                      const float* __restrict__ Wk, const float* __restrict__ bk,
                      const float* __restrict__ Wv, const float* __restrict__ bv,
                      float* __restrict__ Q, float* __restrict__ K, float* __restrict__ V) {
    int row = blockIdx.x;
    int j = threadIdx.x;           // output column, 0..127
    __shared__ float xq[HH], xs[HH];
    xq[j] = Qin[row * HH + j];
    xs[j] = seqs[row * HH + j];
    __syncthreads();
    const float* wq = Wq + j * HH;
    const float* wk = Wk + j * HH;
    const float* wv = Wv + j * HH;
    float aq = 0.f, ak = 0.f, av = 0.f;
    #pragma unroll 4
    for (int k = 0; k < HH; k++) {
        aq += xq[k] * wq[k];
        ak += xs[k] * wk[k];
        av += xs[k] * wv[k];
    }
    Q[row * HH + j] = aq + bq[j];
    K[row * HH + j] = ak + bk[j];
    V[row * HH + j] = av + bv[j];
}

// -------- fused attention: scores + softmax + AV for one (b,q), 4 heads ----
// score[n,k] = Qh[n] . (K[k] + posK[k] + timeK[t[b,q,k]]) over head slice n
// out[n,d]   = sum_k p[k] * (V[k] + posV[k] + timeV[t[b,q,k]])[n,d]
__global__ void k_attn(const float* __restrict__ Q, const float* __restrict__ K,
                       const float* __restrict__ V,
                       const float* __restrict__ posK, const float* __restrict__ posV,
                       const float* __restrict__ timeK, const float* __restrict__ timeV,
                       const int* __restrict__ tm, const int* __restrict__ log_seqs,
                       float* __restrict__ attn_out) {
    int row = blockIdx.x;           // b*L + q
    int b = row / LL, q = row - b * LL;
    int n = threadIdx.x >> 6;       // head = wave id
    int lane = threadIdx.x & 63;

    __shared__ float sc[NHEAD][LL];     // probabilities
    __shared__ float qv[NHEAD][HDIM];   // per-head Q vector

    if (lane < HDIM) qv[n][lane] = Q[row * HH + n * HDIM + lane];
    __syncthreads();

    bool qpad = (log_seqs[row] == 0);
    const int tbase = row * LL;

    // each lane owns keys k = lane, lane+64, ... (max 4)
    float sreg[4];
    int cnt = 0;
    for (int k = lane; k < LL; k += 64) {
        float s;
        if (qpad || k > q) {
            s = PADV;
        } else {
            int t = tm[tbase + k];
            const float* Kp = K + (b * LL + k) * HH + n * HDIM;
            const float* pk = posK + k * HH + n * HDIM;
            const float* tk = timeK + t * HH + n * HDIM;
            s = 0.f;
            #pragma unroll 8
            for (int d = 0; d < HDIM; d++)
                s += qv[n][d] * (Kp[d] + pk[d] + tk[d]);
            s *= INV_SCALE;
        }
        sreg[cnt++] = s;
    }
    // wave softmax
    float m = -3.0e38f;
    for (int j = 0; j < cnt; j++) m = fmaxf(m, sreg[j]);
    for (int off = 32; off; off >>= 1) m = fmaxf(m, __shfl_xor(m, off));
    float sum = 0.f;
    for (int j = 0; j < cnt; j++) { float e = __expf(sreg[j] - m); sreg[j] = e; sum += e; }
    for (int off = 32; off; off >>= 1) sum += __shfl_xor(sum, off);
    float inv = 1.f / sum;
    {
        int j = 0;
        for (int k = lane; k < LL; k += 64) sc[n][k] = sreg[j++] * inv;
    }
    __syncthreads();

    // AV: lanes split keys into even/odd streams; d = lane&31
    int half = lane >> 5, d = lane & 31;
    float acc = 0.f;
    for (int k = half; k < LL; k += 2) {
        float p = sc[n][k];
        int t = tm[tbase + k];
        acc += p * (V[(b * LL + k) * HH + n * HDIM + d]
                    + posV[k * HH + n * HDIM + d]
                    + timeV[t * HH + n * HDIM + d]);
    }
    acc += __shfl_xor(acc, 32);
    if (half == 0) attn_out[row * HH + n * HDIM + d] = acc;
}

// -------- FFN part 1: h1 = relu(x @ W1^T + b1) --------
__global__ void k_ff1(const float* __restrict__ x, const float* __restrict__ W1,
                      const float* __restrict__ b1, float* __restrict__ h1) {
    int row = blockIdx.x;
    int j = threadIdx.x;
    __shared__ float xr[HH];
    xr[j] = x[row * HH + j];
    __syncthreads();
    const float* w = W1 + j * HH;
    float a = 0.f;
    #pragma unroll 4
    for (int k = 0; k < HH; k++) a += xr[k] * w[k];
    a += b1[j];
    h1[row * HH + j] = a > 0.f ? a : 0.f;
}

// -------- FFN part 2: out = (h1 @ W2^T + b2 + x) * keep --------
__global__ void k_ff2(const float* __restrict__ h1, const float* __restrict__ x,
                      const float* __restrict__ W2, const float* __restrict__ b2,
                      const int* __restrict__ log_seqs, float* __restrict__ out) {
    int row = blockIdx.x;
    int j = threadIdx.x;
    __shared__ float xr[HH];
    xr[j] = h1[row * HH + j];
    __syncthreads();
    const float* w = W2 + j * HH;
    float a = 0.f;
    #pragma unroll 4
    for (int k = 0; k < HH; k++) a += xr[k] * w[k];
    a += b2[j] + x[row * HH + j];
    out[row * HH + j] = (log_seqs[row] == 0) ? 0.f : a;
}

// -------- logits: out[o] = feats[row] . item_emb[idx] --------
__global__ void k_logits(const float* __restrict__ feats, const float* __restrict__ item_emb,
                         const int* __restrict__ pos, const int* __restrict__ neg,
                         float* __restrict__ out) {
    int o = blockIdx.x;             // 0..2*BL-1 : pos block then neg block
    int row = (o < BL) ? o : (o - BL);
    const int* idxp = (o < BL) ? pos : neg;
    int idx = idxp[row];
    int h = threadIdx.x;
    float v = feats[row * HH + h] * item_emb[idx * HH + h];
    for (int off = 32; off; off >>= 1) v += __shfl_xor(v, off);
    __shared__ float r[2];
    if ((h & 63) == 0) r[h >> 6] = v;
    __syncthreads();
    if (h == 0) out[o] = r[0] + r[1];
}

extern "C" void kernel_launch(void* const* d_in, const int* in_sizes, int n_in,
                              void* d_out, int out_size, void* d_ws, size_t ws_size,
                              hipStream_t stream) {
    const int* log_seqs   = (const int*)d_in[1];
    const int* tm         = (const int*)d_in[2];
    const int* pos_seqs   = (const int*)d_in[3];
    const int* neg_seqs   = (const int*)d_in[4];
    const float* item_emb = (const float*)d_in[5];
    const float* posK     = (const float*)d_in[6];
    const float* posV     = (const float*)d_in[7];
    const float* timeK    = (const float*)d_in[8];
    const float* timeV    = (const float*)d_in[9];
    const float* attn_g   = (const float*)d_in[10];
    const float* attn_b   = (const float*)d_in[11];
    const float* Wq       = (const float*)d_in[12];
    const float* bq       = (const float*)d_in[13];
    const float* Wk       = (const float*)d_in[14];
    const float* bk       = (const float*)d_in[15];
    const float* Wv       = (const float*)d_in[16];
    const float* bv       = (const float*)d_in[17];
    const float* fwd_g    = (const float*)d_in[18];
    const float* fwd_b    = (const float*)d_in[19];
    const float* W1       = (const float*)d_in[20];
    const float* b1       = (const float*)d_in[21];
    const float* W2       = (const float*)d_in[22];
    const float* b2       = (const float*)d_in[23];
    const float* last_g   = (const float*)d_in[24];
    const float* last_b   = (const float*)d_in[25];

    float* seqs = (float*)d_ws;            // 7 buffers x B*L*H f32 = ~5.7 MB
    float* Qin  = seqs + (size_t)BL * HH;
    float* Qb   = Qin  + (size_t)BL * HH;
    float* Kb   = Qb   + (size_t)BL * HH;
    float* Vb   = Kb   + (size_t)BL * HH;
    float* att  = Vb   + (size_t)BL * HH;
    float* h1   = att  + (size_t)BL * HH;

    k_embed<<<BL, HH, 0, stream>>>(log_seqs, item_emb, seqs);

    for (int i = 0; i < NBLK; i++) {
        k_ln<<<BL, HH, 0, stream>>>(seqs, nullptr, attn_g + i * HH, attn_b + i * HH, Qin);
        k_qkv<<<BL, HH, 0, stream>>>(Qin, seqs,
                                     Wq + (size_t)i * HH * HH, bq + i * HH,
                                     Wk + (size_t)i * HH * HH, bk + i * HH,
                                     Wv + (size_t)i * HH * HH, bv + i * HH,
                                     Qb, Kb, Vb);
        k_attn<<<BL, 256, 0, stream>>>(Qb, Kb, Vb, posK, posV, timeK, timeV, tm, log_seqs, att);
        // seqs = LN(Qin + att)
        k_ln<<<BL, HH, 0, stream>>>(Qin, att, fwd_g + i * HH, fwd_b + i * HH, seqs);
        k_ff1<<<BL, HH, 0, stream>>>(seqs, W1 + (size_t)i * HH * HH, b1 + i * HH, h1);
        // in-place safe: each thread reads x[row,j] before writing out[row,j]
        k_ff2<<<BL, HH, 0, stream>>>(h1, seqs, W2 + (size_t)i * HH * HH, b2 + i * HH, log_seqs, seqs);
    }

    float* feats = Qin;  // reuse
    k_ln<<<BL, HH, 0, stream>>>(seqs, nullptr, last_g, last_b, feats);
    k_logits<<<2 * BL, HH, 0, stream>>>(feats, item_emb, pos_seqs, neg_seqs, (float*)d_out);
}

// Round 3
// 377.504 us; speedup vs baseline: 1.2089x; 1.2089x over previous
//
#include <hip/hip_runtime.h>
#include <hip/hip_bf16.h>

#define BB 8
#define LL 200
#define HH 128
#define NHEAD 4
#define HDIM 32
#define NBLK 2
#define BL (BB * LL)

static constexpr float SQRT_H    = 11.313708498984761f;   // sqrt(128)
static constexpr float INV_SCALE = 0.17677669529663687f;  // 1/sqrt(32)
static constexpr float PADV      = -4294967295.0f;        // -2^32+1

// ---- fused [embed]+LN+QKV: one block per row, 128 threads -----------------
// x    = seqs_in ? seqs_in[row] : item_emb[log[row]]*sqrt(H)*keep
// xq   = LN(x)*g+b        (Qin, saved for residual)
// Q    = (xq@Wq^T+bq) * INV_SCALE                     (pre-scaled)
// K    = x @Wk^T+bk + posK[l]                          (pos fused)
// V    = x @Wv^T+bv + posV[l]
__global__ void k_lnqkv(const float* __restrict__ seqs_in,
                        const int* __restrict__ log_seqs,
                        const float* __restrict__ item_emb,
                        const float* __restrict__ g, const float* __restrict__ bia,
                        const float* __restrict__ Wq, const float* __restrict__ bq,
                        const float* __restrict__ Wk, const float* __restrict__ bk,
                        const float* __restrict__ Wv, const float* __restrict__ bv,
                        const float* __restrict__ posK, const float* __restrict__ posV,
                        float* __restrict__ Qin, float* __restrict__ Q,
                        float* __restrict__ K, float* __restrict__ V) {
    int row = blockIdx.x;
    int l = row % LL;
    int h = threadIdx.x;              // 0..127
    __shared__ float xs[HH], xq[HH];
    float v;
    if (seqs_in) {
        v = seqs_in[row * HH + h];
    } else {
        int idx = log_seqs[row];
        v = (idx == 0) ? 0.f : item_emb[(size_t)idx * HH + h] * SQRT_H;
    }
    xs[h] = v;
    // LN reduce
    float s = v, s2 = v * v;
    for (int off = 32; off; off >>= 1) {
        s  += __shfl_xor(s, off);
        s2 += __shfl_xor(s2, off);
    }
    __shared__ float r1[2], r2[2];
    if ((h & 63) == 0) { r1[h >> 6] = s; r2[h >> 6] = s2; }
    __syncthreads();
    float mean = (r1[0] + r1[1]) * (1.f / HH);
    float var  = (r2[0] + r2[1]) * (1.f / HH) - mean * mean;
    float inv = 1.f / sqrtf(var + 1e-8f);
    float q_ln = (v - mean) * inv * g[h] + bia[h];
    xq[h] = q_ln;
    Qin[row * HH + h] = q_ln;
    __syncthreads();

    const float4* wq = (const float4*)(Wq + (size_t)h * HH);
    const float4* wk = (const float4*)(Wk + (size_t)h * HH);
    const float4* wv = (const float4*)(Wv + (size_t)h * HH);
    const float4* xq4 = (const float4*)xq;
    const float4* xs4 = (const float4*)xs;
    float aq = 0.f, ak = 0.f, av = 0.f;
    #pragma unroll 8
    for (int i = 0; i < HH / 4; i++) {
        float4 a = xq4[i], x = xs4[i];
        float4 q4 = wq[i], k4 = wk[i], v4 = wv[i];
        aq += a.x * q4.x + a.y * q4.y + a.z * q4.z + a.w * q4.w;
        ak += x.x * k4.x + x.y * k4.y + x.z * k4.z + x.w * k4.w;
        av += x.x * v4.x + x.y * v4.y + x.z * v4.z + x.w * v4.w;
    }
    Q[row * HH + h] = (aq + bq[h]) * INV_SCALE;
    K[row * HH + h] = ak + bk[h] + posK[l * HH + h];
    V[row * HH + h] = av + bv[h] + posV[l * HH + h];
}

// ---- fused attention: one block per (b,q) row, 4 waves = 4 heads ----------
__global__ void k_attn(const float* __restrict__ Q, const float* __restrict__ K,
                       const float* __restrict__ V,
                       const float* __restrict__ timeK, const float* __restrict__ timeV,
                       const int* __restrict__ tm, const int* __restrict__ log_seqs,
                       float* __restrict__ attn_out) {
    int row = blockIdx.x;           // b*L + q
    int b = row / LL, q = row - b * LL;
    int n = threadIdx.x >> 6;       // head = wave id
    int lane = threadIdx.x & 63;

    __shared__ float sc[NHEAD][LL];     // probabilities
    __shared__ float qsh[HH];
    __shared__ int   tms[LL];

    for (int k = threadIdx.x; k < LL; k += 256) tms[k] = tm[(size_t)row * LL + k];
    if (threadIdx.x < HH) qsh[threadIdx.x] = Q[row * HH + threadIdx.x];
    __syncthreads();

    // per-head Q vector into registers (LDS broadcast reads)
    float4 qv[8];
    const float4* qp = (const float4*)(qsh + n * HDIM);
    #pragma unroll
    for (int i = 0; i < 8; i++) qv[i] = qp[i];

    bool qpad = (log_seqs[row] == 0);

    // scores: each lane owns keys k = lane, lane+64, ... (max 4)
    float sreg[4];
    int cnt = 0;
    for (int k = lane; k < LL; k += 64) {
        float s;
        if (qpad || k > q) {
            s = PADV;
        } else {
            int t = tms[k];
            const float4* Kp = (const float4*)(K + (size_t)(b * LL + k) * HH + n * HDIM);
            const float4* Tp = (const float4*)(timeK + (size_t)t * HH + n * HDIM);
            float s0 = 0.f, s1 = 0.f, s2 = 0.f, s3 = 0.f;
            #pragma unroll
            for (int i = 0; i < 8; i++) {
                float4 kk = Kp[i], tt = Tp[i];
                s0 += qv[i].x * (kk.x + tt.x);
                s1 += qv[i].y * (kk.y + tt.y);
                s2 += qv[i].z * (kk.z + tt.z);
                s3 += qv[i].w * (kk.w + tt.w);
            }
            s = (s0 + s1) + (s2 + s3);   // Q pre-scaled by 1/sqrt(HD)
        }
        sreg[cnt++] = s;
    }
    // wave softmax
    float m = -3.0e38f;
    for (int j = 0; j < cnt; j++) m = fmaxf(m, sreg[j]);
    for (int off = 32; off; off >>= 1) m = fmaxf(m, __shfl_xor(m, off));
    float sum = 0.f;
    for (int j = 0; j < cnt; j++) { float e = __expf(sreg[j] - m); sreg[j] = e; sum += e; }
    for (int off = 32; off; off >>= 1) sum += __shfl_xor(sum, off);
    float inv = 1.f / sum;
    {
        int j = 0;
        for (int k = lane; k < LL; k += 64) sc[n][k] = sreg[j++] * inv;
    }
    __syncthreads();

    // AV: lanes split keys even/odd; d = lane&31. p==0 beyond q for non-pad rows.
    int half = lane >> 5, d = lane & 31;
    int kend = qpad ? LL : (q + 1);
    float acc = 0.f;
    for (int k = half; k < kend; k += 2) {
        float p = sc[n][k];
        int t = tms[k];
        acc += p * (V[(size_t)(b * LL + k) * HH + n * HDIM + d]
                    + timeV[(size_t)t * HH + n * HDIM + d]);
    }
    acc += __shfl_xor(acc, 32);
    if (half == 0) attn_out[row * HH + n * HDIM + d] = acc;
}

// ---- fused LN + FF1 + FF2 + keep: one block per row, 128 threads ----------
// y = LN(Qin+att)*g+b ; h1 = relu(y@W1^T+b1) ; out = (h1@W2^T+b2+y)*keep
__global__ void k_lnffn(const float* __restrict__ Qin, const float* __restrict__ att,
                        const float* __restrict__ g, const float* __restrict__ bia,
                        const float* __restrict__ W1, const float* __restrict__ b1,
                        const float* __restrict__ W2, const float* __restrict__ b2,
                        const int* __restrict__ log_seqs, float* __restrict__ out) {
    int row = blockIdx.x;
    int h = threadIdx.x;
    __shared__ float xr[HH], h1s[HH];
    float v = Qin[row * HH + h] + att[row * HH + h];
    float s = v, s2 = v * v;
    for (int off = 32; off; off >>= 1) {
        s  += __shfl_xor(s, off);
        s2 += __shfl_xor(s2, off);
    }
    __shared__ float r1[2], r2[2];
    if ((h & 63) == 0) { r1[h >> 6] = s; r2[h >> 6] = s2; }
    __syncthreads();
    float mean = (r1[0] + r1[1]) * (1.f / HH);
    float var  = (r2[0] + r2[1]) * (1.f / HH) - mean * mean;
    float inv = 1.f / sqrtf(var + 1e-8f);
    float y = (v - mean) * inv * g[h] + bia[h];
    xr[h] = y;
    __syncthreads();

    const float4* w1 = (const float4*)(W1 + (size_t)h * HH);
    const float4* x4 = (const float4*)xr;
    float a = 0.f;
    #pragma unroll 8
    for (int i = 0; i < HH / 4; i++) {
        float4 x = x4[i], w = w1[i];
        a += x.x * w.x + x.y * w.y + x.z * w.z + x.w * w.w;
    }
    a += b1[h];
    h1s[h] = a > 0.f ? a : 0.f;
    __syncthreads();

    const float4* w2 = (const float4*)(W2 + (size_t)h * HH);
    const float4* h4 = (const float4*)h1s;
    float c = 0.f;
    #pragma unroll 8
    for (int i = 0; i < HH / 4; i++) {
        float4 x = h4[i], w = w2[i];
        c += x.x * w.x + x.y * w.y + x.z * w.z + x.w * w.w;
    }
    c += b2[h] + y;
    out[row * HH + h] = (log_seqs[row] == 0) ? 0.f : c;
}

// ---- fused last-LN + pos/neg logits: one block per row --------------------
__global__ void k_lnlogits(const float* __restrict__ seqs,
                           const float* __restrict__ g, const float* __restrict__ bia,
                           const float* __restrict__ item_emb,
                           const int* __restrict__ pos, const int* __restrict__ neg,
                           float* __restrict__ out) {
    int row = blockIdx.x;
    int h = threadIdx.x;
    float v = seqs[row * HH + h];
    float s = v, s2 = v * v;
    for (int off = 32; off; off >>= 1) {
        s  += __shfl_xor(s, off);
        s2 += __shfl_xor(s2, off);
    }
    __shared__ float r1[2], r2[2];
    if ((h & 63) == 0) { r1[h >> 6] = s; r2[h >> 6] = s2; }
    __syncthreads();
    float mean = (r1[0] + r1[1]) * (1.f / HH);
    float var  = (r2[0] + r2[1]) * (1.f / HH) - mean * mean;
    float inv = 1.f / sqrtf(var + 1e-8f);
    float f = (v - mean) * inv * g[h] + bia[h];

    int ip = pos[row], in_ = neg[row];
    float vp = f * item_emb[(size_t)ip * HH + h];
    float vn = f * item_emb[(size_t)in_ * HH + h];
    for (int off = 32; off; off >>= 1) {
        vp += __shfl_xor(vp, off);
        vn += __shfl_xor(vn, off);
    }
    __shared__ float rp[2], rn[2];
    if ((h & 63) == 0) { rp[h >> 6] = vp; rn[h >> 6] = vn; }
    __syncthreads();
    if (h == 0) {
        out[row]      = rp[0] + rp[1];
        out[BL + row] = rn[0] + rn[1];
    }
}

extern "C" void kernel_launch(void* const* d_in, const int* in_sizes, int n_in,
                              void* d_out, int out_size, void* d_ws, size_t ws_size,
                              hipStream_t stream) {
    const int* log_seqs   = (const int*)d_in[1];
    const int* tm         = (const int*)d_in[2];
    const int* pos_seqs   = (const int*)d_in[3];
    const int* neg_seqs   = (const int*)d_in[4];
    const float* item_emb = (const float*)d_in[5];
    const float* posK     = (const float*)d_in[6];
    const float* posV     = (const float*)d_in[7];
    const float* timeK    = (const float*)d_in[8];
    const float* timeV    = (const float*)d_in[9];
    const float* attn_g   = (const float*)d_in[10];
    const float* attn_b   = (const float*)d_in[11];
    const float* Wq       = (const float*)d_in[12];
    const float* bq       = (const float*)d_in[13];
    const float* Wk       = (const float*)d_in[14];
    const float* bk       = (const float*)d_in[15];
    const float* Wv       = (const float*)d_in[16];
    const float* bv       = (const float*)d_in[17];
    const float* fwd_g    = (const float*)d_in[18];
    const float* fwd_b    = (const float*)d_in[19];
    const float* W1       = (const float*)d_in[20];
    const float* b1       = (const float*)d_in[21];
    const float* W2       = (const float*)d_in[22];
    const float* b2       = (const float*)d_in[23];
    const float* last_g   = (const float*)d_in[24];
    const float* last_b   = (const float*)d_in[25];

    float* seqs = (float*)d_ws;            // 6 buffers x B*L*H f32 = ~4.9 MB
    float* Qin  = seqs + (size_t)BL * HH;
    float* Qb   = Qin  + (size_t)BL * HH;
    float* Kb   = Qb   + (size_t)BL * HH;
    float* Vb   = Kb   + (size_t)BL * HH;
    float* att  = Vb   + (size_t)BL * HH;

    for (int i = 0; i < NBLK; i++) {
        k_lnqkv<<<BL, HH, 0, stream>>>(i == 0 ? nullptr : seqs, log_seqs, item_emb,
                                       attn_g + i * HH, attn_b + i * HH,
                                       Wq + (size_t)i * HH * HH, bq + i * HH,
                                       Wk + (size_t)i * HH * HH, bk + i * HH,
                                       Wv + (size_t)i * HH * HH, bv + i * HH,
                                       posK, posV, Qin, Qb, Kb, Vb);
        k_attn<<<BL, 256, 0, stream>>>(Qb, Kb, Vb, timeK, timeV, tm, log_seqs, att);
        k_lnffn<<<BL, HH, 0, stream>>>(Qin, att, fwd_g + i * HH, fwd_b + i * HH,
                                       W1 + (size_t)i * HH * HH, b1 + i * HH,
                                       W2 + (size_t)i * HH * HH, b2 + i * HH,
                                       log_seqs, seqs);
    }
    k_lnlogits<<<BL, HH, 0, stream>>>(seqs, last_g, last_b, item_emb,
                                      pos_seqs, neg_seqs, (float*)d_out);
}

// Round 4
// 294.084 us; speedup vs baseline: 1.5518x; 1.2837x over previous
//
#include <hip/hip_runtime.h>
#include <hip/hip_bf16.h>

#define BB 8
#define LL 200
#define HH 128
#define NHEAD 4
#define HDIM 32
#define NBLK 2
#define BL (BB * LL)
#define NT 257            // TIME_SPAN+1
#define ROWS 8            // rows per block in tiled GEMV kernels

static constexpr float SQRT_H    = 11.313708498984761f;   // sqrt(128)
static constexpr float INV_SCALE = 0.17677669529663687f;  // 1/sqrt(32)
static constexpr float PADV      = -4294967295.0f;        // -2^32+1

// ---- transpose timeK [t][h] -> timeK_T [h][t] (once, reused by both layers)
__global__ void k_timekT(const float* __restrict__ timeK, float* __restrict__ timeK_T) {
    int h = blockIdx.x;            // 0..127
    for (int t = threadIdx.x; t < NT; t += blockDim.x)
        timeK_T[h * NT + t] = timeK[t * HH + h];
}

// ---- fused [embed]+LN+QKV, tiled 8 rows/block, 256 threads ----------------
// Q  = (LN(x)@Wq^T+bq)*INV_SCALE ; K_T[b][h][l] = x@Wk^T+bk+posK ; V = x@Wv^T+bv+posV
__global__ void k_lnqkv(const float* __restrict__ seqs_in,
                        const int* __restrict__ log_seqs,
                        const float* __restrict__ item_emb,
                        const float* __restrict__ g, const float* __restrict__ bia,
                        const float* __restrict__ Wq, const float* __restrict__ bq,
                        const float* __restrict__ Wk, const float* __restrict__ bk,
                        const float* __restrict__ Wv, const float* __restrict__ bv,
                        const float* __restrict__ posK, const float* __restrict__ posV,
                        float* __restrict__ Qin, float* __restrict__ Q,
                        float* __restrict__ K_T, float* __restrict__ V) {
    int row0 = blockIdx.x * ROWS;          // tiles never straddle batches (200%8==0)
    int tid = threadIdx.x;
    int wave = tid >> 6, lane = tid & 63;
    __shared__ float xs[ROWS][HH], xq[ROWS][HH];

    // load + per-row LN: wave w handles rows 2w, 2w+1 (2 elems/lane)
    for (int rr = 0; rr < 2; rr++) {
        int r = wave * 2 + rr;
        int row = row0 + r;
        float v0, v1;
        if (seqs_in) {
            v0 = seqs_in[(size_t)row * HH + lane];
            v1 = seqs_in[(size_t)row * HH + lane + 64];
        } else {
            int idx = log_seqs[row];
            if (idx == 0) { v0 = 0.f; v1 = 0.f; }
            else {
                v0 = item_emb[(size_t)idx * HH + lane] * SQRT_H;
                v1 = item_emb[(size_t)idx * HH + lane + 64] * SQRT_H;
            }
        }
        xs[r][lane] = v0; xs[r][lane + 64] = v1;
        float s = v0 + v1, s2 = v0 * v0 + v1 * v1;
        for (int off = 32; off; off >>= 1) {
            s  += __shfl_xor(s, off);
            s2 += __shfl_xor(s2, off);
        }
        float mean = s * (1.f / HH);
        float var  = s2 * (1.f / HH) - mean * mean;
        float inv  = 1.f / sqrtf(var + 1e-8f);
        float q0 = (v0 - mean) * inv * g[lane]      + bia[lane];
        float q1 = (v1 - mean) * inv * g[lane + 64] + bia[lane + 64];
        xq[r][lane] = q0; xq[r][lane + 64] = q1;
        Qin[(size_t)row * HH + lane]      = q0;
        Qin[(size_t)row * HH + lane + 64] = q1;
    }
    __syncthreads();

    int j  = tid & 127;      // output column
    int rh = tid >> 7;       // 0/1 -> rows rh*4 .. rh*4+3
    const float4* wq4 = (const float4*)(Wq + (size_t)j * HH);
    const float4* wk4 = (const float4*)(Wk + (size_t)j * HH);
    const float4* wv4 = (const float4*)(Wv + (size_t)j * HH);
    float aq[4] = {0,0,0,0}, ak[4] = {0,0,0,0}, av[4] = {0,0,0,0};
    for (int i = 0; i < HH / 4; i++) {
        float4 wq = wq4[i], wk = wk4[i], wv = wv4[i];
        #pragma unroll
        for (int r = 0; r < 4; r++) {
            float4 a = *(const float4*)&xq[rh * 4 + r][i * 4];
            float4 x = *(const float4*)&xs[rh * 4 + r][i * 4];
            aq[r] += a.x * wq.x + a.y * wq.y + a.z * wq.z + a.w * wq.w;
            ak[r] += x.x * wk.x + x.y * wk.y + x.z * wk.z + x.w * wk.w;
            av[r] += x.x * wv.x + x.y * wv.y + x.z * wv.z + x.w * wv.w;
        }
    }
    #pragma unroll
    for (int r = 0; r < 4; r++) {
        int row = row0 + rh * 4 + r;
        int b = row / LL, l = row - b * LL;
        Q[(size_t)row * HH + j] = (aq[r] + bq[j]) * INV_SCALE;
        K_T[((size_t)b * HH + j) * LL + l] = ak[r] + bk[j] + posK[l * HH + j];
        V[(size_t)row * HH + j] = av[r] + bv[j] + posV[l * HH + j];
    }
}

// ---- fused attention: one block per (b,q), 4 waves = 4 heads --------------
__global__ void k_attn(const float* __restrict__ Q, const float* __restrict__ K_T,
                       const float* __restrict__ V,
                       const float* __restrict__ timeK_T, const float* __restrict__ timeV,
                       const int* __restrict__ tm, const int* __restrict__ log_seqs,
                       float* __restrict__ att) {
    int blk = blockIdx.x;
    int b = blk & 7, q = (LL - 1) - (blk >> 3);   // heavy blocks dispatch first
    int row = b * LL + q;
    int n = threadIdx.x >> 6, lane = threadIdx.x & 63;

    __shared__ float sc[NHEAD][LL];    // probabilities
    __shared__ float dts[NHEAD][NT];   // dt[tau] = Qh . timeKh[tau]
    __shared__ float wacc[NHEAD][NT];  // w[tau] = sum_{t[k]=tau} p[k]
    __shared__ float qsh[HH];
    __shared__ int   tms[LL];

    for (int k = threadIdx.x; k < LL; k += 256) tms[k] = tm[(size_t)row * LL + k];
    if (threadIdx.x < HH) qsh[threadIdx.x] = Q[(size_t)row * HH + threadIdx.x];
    // zero per-head scatter bins (head-private -> no cross-wave sync needed)
    #pragma unroll
    for (int i = 0; i < 4; i++) wacc[n][lane + 64 * i] = 0.f;
    if (lane == 0) wacc[n][256] = 0.f;
    __syncthreads();

    bool qpad = (log_seqs[row] == 0);
    const float* qh = qsh + n * HDIM;

    float sreg[4];
    int cnt = 0;
    if (!qpad) {
        // dt table: coalesced column walks of timeK_T
        const float* tkb = timeK_T + (size_t)(n * HDIM) * NT;
        #pragma unroll
        for (int i = 0; i < 4; i++) {
            const float* cp = tkb + lane + 64 * i;
            float a = 0.f;
            #pragma unroll 8
            for (int d = 0; d < HDIM; d++) a += qh[d] * cp[(size_t)d * NT];
            dts[n][lane + 64 * i] = a;
        }
        if (lane == 0) {
            float a = 0.f;
            for (int d = 0; d < HDIM; d++) a += qh[d] * tkb[(size_t)d * NT + 256];
            dts[n][256] = a;
        }
        // kdot: coalesced column walks of K_T (clamped index, masked later)
        const float* ktb = K_T + (size_t)(b * HH + n * HDIM) * LL;
        float kd[4] = {0,0,0,0};
        int imax = q >> 6;
        for (int i = 0; i <= imax; i++) {
            int kc = lane + 64 * i; kc = kc > q ? q : kc;
            const float* cp = ktb + kc;
            float a = 0.f;
            #pragma unroll 8
            for (int d = 0; d < HDIM; d++) a += qh[d] * cp[(size_t)d * LL];
            kd[i] = a;
        }
        #pragma unroll
        for (int i = 0; i < 4; i++) {
            int k = lane + 64 * i;
            if (k < LL) sreg[cnt++] = (k <= q) ? (kd[i] + dts[n][tms[k]]) : PADV;
        }
    } else {
        #pragma unroll
        for (int i = 0; i < 4; i++) { int k = lane + 64 * i; if (k < LL) sreg[cnt++] = PADV; }
    }

    // wave softmax
    float m = -3.0e38f;
    for (int j = 0; j < cnt; j++) m = fmaxf(m, sreg[j]);
    for (int off = 32; off; off >>= 1) m = fmaxf(m, __shfl_xor(m, off));
    float sum = 0.f;
    for (int j = 0; j < cnt; j++) { float e = __expf(sreg[j] - m); sreg[j] = e; sum += e; }
    for (int off = 32; off; off >>= 1) sum += __shfl_xor(sum, off);
    float inv = 1.f / sum;
    {
        int j = 0;
        for (int k = lane; k < LL; k += 64) {
            float p = sreg[j++] * inv;
            sc[n][k] = p;
            if (qpad || k <= q) atomicAdd(&wacc[n][tms[k]], p);   // ds_add_f32
        }
    }
    __syncthreads();

    // AV: half-wave groups, d = lane&31; V and timeV reads are d-coalesced
    int half = lane >> 5, d = lane & 31;
    int kend = qpad ? LL : (q + 1);
    float acc = 0.f;
    const float* vb = V + ((size_t)b * LL) * HH + n * HDIM + d;
    for (int k = half; k < kend; k += 2)
        acc += sc[n][k] * vb[(size_t)k * HH];
    const float* tvb = timeV + n * HDIM + d;
    for (int t = half; t < NT; t += 2)
        acc += wacc[n][t] * tvb[(size_t)t * HH];
    acc += __shfl_xor(acc, 32);
    if (half == 0) att[(size_t)row * HH + n * HDIM + d] = acc;
}

// ---- fused LN + FF1 + FF2 + keep, tiled 8 rows/block, 256 threads ---------
__global__ void k_lnffn(const float* __restrict__ Qin, const float* __restrict__ att,
                        const float* __restrict__ g, const float* __restrict__ bia,
                        const float* __restrict__ W1, const float* __restrict__ b1,
                        const float* __restrict__ W2, const float* __restrict__ b2,
                        const int* __restrict__ log_seqs, float* __restrict__ out) {
    int row0 = blockIdx.x * ROWS;
    int tid = threadIdx.x;
    int wave = tid >> 6, lane = tid & 63;
    __shared__ float xr[ROWS][HH], h1s[ROWS][HH];

    for (int rr = 0; rr < 2; rr++) {
        int r = wave * 2 + rr;
        int row = row0 + r;
        float v0 = Qin[(size_t)row * HH + lane]      + att[(size_t)row * HH + lane];
        float v1 = Qin[(size_t)row * HH + lane + 64] + att[(size_t)row * HH + lane + 64];
        float s = v0 + v1, s2 = v0 * v0 + v1 * v1;
        for (int off = 32; off; off >>= 1) {
            s  += __shfl_xor(s, off);
            s2 += __shfl_xor(s2, off);
        }
        float mean = s * (1.f / HH);
        float var  = s2 * (1.f / HH) - mean * mean;
        float inv  = 1.f / sqrtf(var + 1e-8f);
        xr[r][lane]      = (v0 - mean) * inv * g[lane]      + bia[lane];
        xr[r][lane + 64] = (v1 - mean) * inv * g[lane + 64] + bia[lane + 64];
    }
    __syncthreads();

    int j  = tid & 127;
    int rh = tid >> 7;
    const float4* w1 = (const float4*)(W1 + (size_t)j * HH);
    float a[4] = {0,0,0,0};
    for (int i = 0; i < HH / 4; i++) {
        float4 w = w1[i];
        #pragma unroll
        for (int r = 0; r < 4; r++) {
            float4 x = *(const float4*)&xr[rh * 4 + r][i * 4];
            a[r] += x.x * w.x + x.y * w.y + x.z * w.z + x.w * w.w;
        }
    }
    #pragma unroll
    for (int r = 0; r < 4; r++) {
        float t = a[r] + b1[j];
        h1s[rh * 4 + r][j] = t > 0.f ? t : 0.f;
    }
    __syncthreads();

    const float4* w2 = (const float4*)(W2 + (size_t)j * HH);
    float c[4] = {0,0,0,0};
    for (int i = 0; i < HH / 4; i++) {
        float4 w = w2[i];
        #pragma unroll
        for (int r = 0; r < 4; r++) {
            float4 x = *(const float4*)&h1s[rh * 4 + r][i * 4];
            c[r] += x.x * w.x + x.y * w.y + x.z * w.z + x.w * w.w;
        }
    }
    #pragma unroll
    for (int r = 0; r < 4; r++) {
        int row = row0 + rh * 4 + r;
        float t = c[r] + b2[j] + xr[rh * 4 + r][j];
        out[(size_t)row * HH + j] = (log_seqs[row] == 0) ? 0.f : t;
    }
}

// ---- fused last-LN + pos/neg logits: one block per row --------------------
__global__ void k_lnlogits(const float* __restrict__ seqs,
                           const float* __restrict__ g, const float* __restrict__ bia,
                           const float* __restrict__ item_emb,
                           const int* __restrict__ pos, const int* __restrict__ neg,
                           float* __restrict__ out) {
    int row = blockIdx.x;
    int h = threadIdx.x;
    float v = seqs[(size_t)row * HH + h];
    float s = v, s2 = v * v;
    for (int off = 32; off; off >>= 1) {
        s  += __shfl_xor(s, off);
        s2 += __shfl_xor(s2, off);
    }
    __shared__ float r1[2], r2[2];
    if ((h & 63) == 0) { r1[h >> 6] = s; r2[h >> 6] = s2; }
    __syncthreads();
    float mean = (r1[0] + r1[1]) * (1.f / HH);
    float var  = (r2[0] + r2[1]) * (1.f / HH) - mean * mean;
    float inv = 1.f / sqrtf(var + 1e-8f);
    float f = (v - mean) * inv * g[h] + bia[h];

    int ip = pos[row], in_ = neg[row];
    float vp = f * item_emb[(size_t)ip * HH + h];
    float vn = f * item_emb[(size_t)in_ * HH + h];
    for (int off = 32; off; off >>= 1) {
        vp += __shfl_xor(vp, off);
        vn += __shfl_xor(vn, off);
    }
    __shared__ float rp[2], rn[2];
    if ((h & 63) == 0) { rp[h >> 6] = vp; rn[h >> 6] = vn; }
    __syncthreads();
    if (h == 0) {
        out[row]      = rp[0] + rp[1];
        out[BL + row] = rn[0] + rn[1];
    }
}

extern "C" void kernel_launch(void* const* d_in, const int* in_sizes, int n_in,
                              void* d_out, int out_size, void* d_ws, size_t ws_size,
                              hipStream_t stream) {
    const int* log_seqs   = (const int*)d_in[1];
    const int* tm         = (const int*)d_in[2];
    const int* pos_seqs   = (const int*)d_in[3];
    const int* neg_seqs   = (const int*)d_in[4];
    const float* item_emb = (const float*)d_in[5];
    const float* posK     = (const float*)d_in[6];
    const float* posV     = (const float*)d_in[7];
    const float* timeK    = (const float*)d_in[8];
    const float* timeV    = (const float*)d_in[9];
    const float* attn_g   = (const float*)d_in[10];
    const float* attn_b   = (const float*)d_in[11];
    const float* Wq       = (const float*)d_in[12];
    const float* bq       = (const float*)d_in[13];
    const float* Wk       = (const float*)d_in[14];
    const float* bk       = (const float*)d_in[15];
    const float* Wv       = (const float*)d_in[16];
    const float* bv       = (const float*)d_in[17];
    const float* fwd_g    = (const float*)d_in[18];
    const float* fwd_b    = (const float*)d_in[19];
    const float* W1       = (const float*)d_in[20];
    const float* b1       = (const float*)d_in[21];
    const float* W2       = (const float*)d_in[22];
    const float* b2       = (const float*)d_in[23];
    const float* last_g   = (const float*)d_in[24];
    const float* last_b   = (const float*)d_in[25];

    float* seqs = (float*)d_ws;            // 6 x B*L*H f32 + timeK_T = ~5.1 MB
    float* Qin  = seqs + (size_t)BL * HH;
    float* Qb   = Qin  + (size_t)BL * HH;
    float* KT   = Qb   + (size_t)BL * HH;
    float* Vb   = KT   + (size_t)BL * HH;
    float* att  = Vb   + (size_t)BL * HH;
    float* tkT  = att  + (size_t)BL * HH;  // 128*257 floats

    k_timekT<<<HH, 256, 0, stream>>>(timeK, tkT);

    for (int i = 0; i < NBLK; i++) {
        k_lnqkv<<<BL / ROWS, 256, 0, stream>>>(i == 0 ? nullptr : seqs, log_seqs, item_emb,
                                               attn_g + i * HH, attn_b + i * HH,
                                               Wq + (size_t)i * HH * HH, bq + i * HH,
                                               Wk + (size_t)i * HH * HH, bk + i * HH,
                                               Wv + (size_t)i * HH * HH, bv + i * HH,
                                               posK, posV, Qin, Qb, KT, Vb);
        k_attn<<<BL, 256, 0, stream>>>(Qb, KT, Vb, tkT, timeV, tm, log_seqs, att);
        k_lnffn<<<BL / ROWS, 256, 0, stream>>>(Qin, att, fwd_g + i * HH, fwd_b + i * HH,
                                               W1 + (size_t)i * HH * HH, b1 + i * HH,
                                               W2 + (size_t)i * HH * HH, b2 + i * HH,
                                               log_seqs, seqs);
    }
    k_lnlogits<<<BL, HH, 0, stream>>>(seqs, last_g, last_b, item_emb,
                                      pos_seqs, neg_seqs, (float*)d_out);
}